// Round 2
// baseline (5997.635 us; speedup 1.0000x reference)
//
#include <hip/hip_runtime.h>
#include <hip/hip_bf16.h>
#include <math.h>

#define BB 4
#define SEQ 8192
#define DIM 512
#define GG 32
#define NPG 256
#define QKD 128
#define HIDD 512

typedef unsigned short u16;
typedef unsigned int u32;

__device__ __forceinline__ float bf2f(u16 u) { return __uint_as_float(((u32)u) << 16); }
__device__ __forceinline__ float bflo(u32 u) { return __uint_as_float(u << 16); }
__device__ __forceinline__ float bfhi(u32 u) { return __uint_as_float(u & 0xFFFF0000u); }
__device__ __forceinline__ u16 f2bf(float f) {
  u32 b = __float_as_uint(f);
  return (u16)((b + 0x7FFFu + ((b >> 16) & 1u)) >> 16);
}
__device__ __forceinline__ float silu_f(float x) { return x / (1.f + expf(-x)); }

// ---------------- Kernel 1: LayerNorm + global seq-shift scatter ----------------
// xs[b,s,0:256]   = LN(x[b,s-1])[0:256]  (0 for s==0)
// xs[b,s,256:512] = LN(x[b,s])[256:512]
__global__ __launch_bounds__(256) void k_ln(const float* __restrict__ x,
    const float* __restrict__ lg, const float* __restrict__ lb, float* __restrict__ xs) {
  const int row = blockIdx.x;               // b*SEQ + s
  const int s = row & (SEQ - 1);
  const int t = threadIdx.x;
  const float* xr = x + (size_t)row * DIM;
  float v0 = xr[t], v1 = xr[t + 256];
  float sum = v0 + v1, sq = v0 * v0 + v1 * v1;
  #pragma unroll
  for (int o = 32; o; o >>= 1) { sum += __shfl_down(sum, o); sq += __shfl_down(sq, o); }
  __shared__ float sm[8];
  const int w = t >> 6;
  if ((t & 63) == 0) { sm[w] = sum; sm[4 + w] = sq; }
  __syncthreads();
  if (t == 0) {
    float S = sm[0] + sm[1] + sm[2] + sm[3];
    float Q = sm[4] + sm[5] + sm[6] + sm[7];
    float mu = S * (1.f / DIM);
    float var = Q * (1.f / DIM) - mu * mu;
    sm[0] = mu; sm[4] = rsqrtf(var + 1e-5f);
  }
  __syncthreads();
  const float mu = sm[0], rs = sm[4];
  float y0 = (v0 - mu) * rs * lg[t] + lb[t];
  float y1 = (v1 - mu) * rs * lg[t + 256] + lb[t + 256];
  xs[(size_t)row * DIM + t + 256] = y1;
  if (s + 1 < SEQ) xs[(size_t)(row + 1) * DIM + t] = y0;   // same batch (s+1<SEQ)
  if (s == 0) xs[(size_t)row * DIM + t] = 0.f;
}

// ---------------- Kernel 2: fused GEMM xs @ [w_qk | w_hidden | w_gate] ----------------
// N segments: [0,128)->qk f32; [128,640)->hidden bf16; [640,1152)->gate bf16; [1152,1664)->silu(xg) bf16
__global__ __launch_bounds__(256) void k_gemm1(const float* __restrict__ xs,
    const float* __restrict__ w_qk, const float* __restrict__ w_hidden,
    const float* __restrict__ w_gate, float* __restrict__ qk,
    u16* __restrict__ hid, u16* __restrict__ gate, u16* __restrict__ xg) {
  __shared__ float As[32][68];   // As[kk][r] = A[m0+r][k0+kk]
  __shared__ float Bs[32][68];   // Bs[kk][c] = B[k0+kk][n0+c]
  const int t = threadIdx.x;
  const int m0 = blockIdx.x * 64;
  const int n0 = blockIdx.y * 64;
  const float* bptr; int ld, coff;
  if (n0 < 128)       { bptr = w_qk;     ld = 128;  coff = n0; }
  else if (n0 < 1152) { bptr = w_hidden; ld = 1024; coff = n0 - 128; }
  else                { bptr = w_gate;   ld = 512;  coff = n0 - 1152; }
  float acc[4][4];
  #pragma unroll
  for (int i = 0; i < 4; ++i)
    #pragma unroll
    for (int j = 0; j < 4; ++j) acc[i][j] = 0.f;
  const int ar = t >> 3, ac = (t & 7) << 2;
  const int bk = t >> 4, bc = (t & 15) << 2;
  const int rb = (t >> 4) << 2, cb = (t & 15) << 2;
  for (int k0 = 0; k0 < DIM; k0 += 32) {
    float4 a0 = *(const float4*)(xs + (size_t)(m0 + ar) * DIM + k0 + ac);
    float4 a1 = *(const float4*)(xs + (size_t)(m0 + ar + 32) * DIM + k0 + ac);
    float4 b0 = *(const float4*)(bptr + (size_t)(k0 + bk) * ld + coff + bc);
    float4 b1 = *(const float4*)(bptr + (size_t)(k0 + bk + 16) * ld + coff + bc);
    __syncthreads();
    As[ac + 0][ar] = a0.x; As[ac + 1][ar] = a0.y; As[ac + 2][ar] = a0.z; As[ac + 3][ar] = a0.w;
    As[ac + 0][ar + 32] = a1.x; As[ac + 1][ar + 32] = a1.y; As[ac + 2][ar + 32] = a1.z; As[ac + 3][ar + 32] = a1.w;
    *(float4*)&Bs[bk][bc] = b0;
    *(float4*)&Bs[bk + 16][bc] = b1;
    __syncthreads();
    #pragma unroll
    for (int kk = 0; kk < 32; ++kk) {
      const float4 av = *(const float4*)&As[kk][rb];
      const float4 bv = *(const float4*)&Bs[kk][cb];
      acc[0][0] += av.x * bv.x; acc[0][1] += av.x * bv.y; acc[0][2] += av.x * bv.z; acc[0][3] += av.x * bv.w;
      acc[1][0] += av.y * bv.x; acc[1][1] += av.y * bv.y; acc[1][2] += av.y * bv.z; acc[1][3] += av.y * bv.w;
      acc[2][0] += av.z * bv.x; acc[2][1] += av.z * bv.y; acc[2][2] += av.z * bv.z; acc[2][3] += av.z * bv.w;
      acc[3][0] += av.w * bv.x; acc[3][1] += av.w * bv.y; acc[3][2] += av.w * bv.z; acc[3][3] += av.w * bv.w;
    }
  }
  #pragma unroll
  for (int i = 0; i < 4; ++i) {
    const size_t m = m0 + rb + i;
    #pragma unroll
    for (int j = 0; j < 4; ++j) {
      const int n = n0 + cb + j;
      float v = acc[i][j];
      if (n0 < 128)       qk[m * QKD + n] = v;
      else if (n0 < 640)  hid[m * HIDD + (n - 128)] = f2bf(v);
      else if (n0 < 1152) gate[m * HIDD + (n - 640)] = f2bf(v);
      else                xg[m * HIDD + (n - 1152)] = f2bf(silu_f(v));
    }
  }
}

// ---------------- Kernel 3: qk_mean over each group's 256 rows ----------------
__global__ __launch_bounds__(128) void k_qkmean(const float* __restrict__ qk, float* __restrict__ qm) {
  const int bg = blockIdx.x;                 // b*G+g ; group rows are contiguous
  const int c = threadIdx.x;
  const float* p = qk + (size_t)bg * NPG * QKD + c;
  float s = 0.f;
  for (int i = 0; i < NPG; ++i) s += p[(size_t)i * QKD];
  qm[(size_t)bg * QKD + c] = s * (1.f / NPG);
}

// ---------------- Kernel 4: attention per (b,g,h,chunk of 32 rows) ----------------
__global__ __launch_bounds__(256) void k_attn(const float* __restrict__ qk,
    const float* __restrict__ qm, const float* __restrict__ g4, const float* __restrict__ b4,
    const float* __restrict__ g2, const float* __restrict__ b2,
    const u16* __restrict__ hid, const u16* __restrict__ gate, u16* __restrict__ out4) {
  __shared__ u16 Ks[256][68];    // bf16 K_all[h]  (row stride 136B, 8B-aligned)
  __shared__ u16 Qs[32][68];     // bf16 Q chunk
  __shared__ u16 Pa[32][260];    // bf16 attn weights
  const int t = threadIdx.x;
  const int blk = blockIdx.x;
  const int chunk = blk & 7, h = (blk >> 3) & 3, g = (blk >> 5) & 31, b = blk >> 10;
  const int bg = (b << 5) | g;
  const int cbase = (h & 1) << 6;
  const size_t grpRow = (size_t)bg * NPG;
  // per-thread column params (thread's d = t&63 is fixed across staging iterations)
  const int d = t & 63, ccol = cbase + d;
  const float qmv = qm[(size_t)bg * QKD + ccol];
  const float qof = qmv * g4[ccol] + b4[ccol];
  const float kof = qmv * g4[QKD + ccol] + b4[QKD + ccol];
  const float qsc = qmv * g4[2 * QKD + ccol] + b4[2 * QKD + ccol];
  const float ksc = qmv * g4[3 * QKD + ccol] + b4[3 * QKD + ccol];
  const float qso = qmv * g2[ccol] + b2[ccol];
  const float kso = qmv * g2[QKD + ccol] + b2[QKD + ccol];
  // stage K_all[h] : 256 x 64
  for (int j = (t >> 6); j < NPG; j += 4) {
    float kv;
    if (h < 2) kv = qk[(grpRow + j) * QKD + ccol] * ksc + kof;
    else {
      float prev = (j > 0) ? (qk[(grpRow + j - 1) * QKD + ccol] * ksc + kof) : 0.f;
      kv = prev * ksc + kso;
    }
    Ks[j][d] = f2bf(kv);
  }
  // stage Q chunk : 32 x 64
  for (int i = (t >> 6); i < 32; i += 4) {
    int gi = (chunk << 5) + i;
    float qv;
    if (h < 2) qv = qk[(grpRow + gi) * QKD + ccol] * qsc + qof;
    else {
      float prev = (gi > 0) ? (qk[(grpRow + gi - 1) * QKD + ccol] * qsc + qof) : 0.f;
      qv = prev * qsc + qso;
    }
    Qs[i][d] = f2bf(qv);
  }
  __syncthreads();
  // sim: lane (i = t>>3, c = t&7) owns row i, columns j = c + 8*jj
  const int i = t >> 3, c = t & 7;
  const int gi = (chunk << 5) + i;
  float s[32];
  #pragma unroll
  for (int jj = 0; jj < 32; ++jj) s[jj] = 0.f;
  for (int d4 = 0; d4 < 16; ++d4) {
    ushort4 qu = *(const ushort4*)&Qs[i][d4 << 2];
    float q0 = bf2f(qu.x), q1 = bf2f(qu.y), q2 = bf2f(qu.z), q3 = bf2f(qu.w);
    #pragma unroll
    for (int jj = 0; jj < 32; ++jj) {
      ushort4 ku = *(const ushort4*)&Ks[c + (jj << 3)][d4 << 2];
      s[jj] += q0 * bf2f(ku.x) + q1 * bf2f(ku.y) + q2 * bf2f(ku.z) + q3 * bf2f(ku.w);
    }
  }
  // causal softmax across the 8 lanes sharing row i
  const float scl = 0.17677669529663687f;   // 1/sqrt(HD=32)
  float mx = -3.4e38f;
  #pragma unroll
  for (int jj = 0; jj < 32; ++jj) {
    s[jj] *= scl;
    if (c + (jj << 3) <= gi) mx = fmaxf(mx, s[jj]);
  }
  #pragma unroll
  for (int o = 1; o < 8; o <<= 1) mx = fmaxf(mx, __shfl_xor(mx, o));
  float sum = 0.f;
  #pragma unroll
  for (int jj = 0; jj < 32; ++jj) {
    float ev = (c + (jj << 3) <= gi) ? expf(s[jj] - mx) : 0.f;
    s[jj] = ev; sum += ev;
  }
  #pragma unroll
  for (int o = 1; o < 8; o <<= 1) sum += __shfl_xor(sum, o);
  const float inv = 1.f / sum;
  #pragma unroll
  for (int jj = 0; jj < 32; ++jj) Pa[i][c + (jj << 3)] = f2bf(s[jj] * inv);
  __syncthreads();
  // PV: out[i][e0..e0+63] = sum_j attn[i][j] * hidden[grp j][e]  (V is bf16)
  float acc[64];
  #pragma unroll
  for (int q = 0; q < 64; ++q) acc[q] = 0.f;
  const int e0 = c << 6;
  const int jhi = (chunk << 5) + ((t >> 6) << 3) + 7;   // wave-uniform causal bound
  const u16* hb = hid + grpRow * HIDD + e0;
  for (int j = 0; j <= jhi; ++j) {
    float aw = bf2f(Pa[i][j]);
    const uint4* hr = (const uint4*)(hb + (size_t)j * HIDD);   // 16B = 8 bf16
    #pragma unroll
    for (int q = 0; q < 8; ++q) {
      uint4 hv = hr[q];
      acc[8 * q + 0] += aw * bflo(hv.x); acc[8 * q + 1] += aw * bfhi(hv.x);
      acc[8 * q + 2] += aw * bflo(hv.y); acc[8 * q + 3] += aw * bfhi(hv.y);
      acc[8 * q + 4] += aw * bflo(hv.z); acc[8 * q + 5] += aw * bfhi(hv.z);
      acc[8 * q + 6] += aw * bflo(hv.w); acc[8 * q + 7] += aw * bfhi(hv.w);
    }
  }
  // epilogue: silu(out) * gate -> out4 bf16 at [b,s, h*512 + e]
  const size_t srow = grpRow + (chunk << 5) + i;
  const u16* gp = gate + srow * HIDD + e0;
  u16* op = out4 + srow * (4 * HIDD) + (h << 9) + e0;
  #pragma unroll
  for (int q = 0; q < 16; ++q) {
    ushort4 gu = *(const ushort4*)(gp + (q << 2));
    ushort4 ov;
    ov.x = f2bf(silu_f(acc[4 * q])     * bf2f(gu.x));
    ov.y = f2bf(silu_f(acc[4 * q + 1]) * bf2f(gu.y));
    ov.z = f2bf(silu_f(acc[4 * q + 2]) * bf2f(gu.z));
    ov.w = f2bf(silu_f(acc[4 * q + 3]) * bf2f(gu.w));
    *(ushort4*)(op + (q << 2)) = ov;
  }
}

// ---------------- Kernel 5: final GEMM residual(2560) @ w_out + epilogue ----------------
__global__ __launch_bounds__(256) void k_gemm2(const u16* __restrict__ hid,
    const u16* __restrict__ out4, const float* __restrict__ w_out,
    const u16* __restrict__ xg, const float* __restrict__ xs, float* __restrict__ out) {
  __shared__ float As[32][68];
  __shared__ float Bs[32][68];
  const int t = threadIdx.x;
  const int m0 = blockIdx.x * 64, n0 = blockIdx.y * 64;
  float acc[4][4];
  #pragma unroll
  for (int i = 0; i < 4; ++i)
    #pragma unroll
    for (int j = 0; j < 4; ++j) acc[i][j] = 0.f;
  const int ar = t >> 3, ac = (t & 7) << 2;
  const int bk = t >> 4, bc = (t & 15) << 2;
  const int rb = (t >> 4) << 2, cb = (t & 15) << 2;
  for (int k0 = 0; k0 < 2560; k0 += 32) {
    ushort4 u0, u1;
    if (k0 < 512) {
      u0 = *(const ushort4*)(hid + (size_t)(m0 + ar) * HIDD + k0 + ac);
      u1 = *(const ushort4*)(hid + (size_t)(m0 + ar + 32) * HIDD + k0 + ac);
    } else {
      u0 = *(const ushort4*)(out4 + (size_t)(m0 + ar) * 2048 + (k0 - 512) + ac);
      u1 = *(const ushort4*)(out4 + (size_t)(m0 + ar + 32) * 2048 + (k0 - 512) + ac);
    }
    float4 a0 = make_float4(bf2f(u0.x), bf2f(u0.y), bf2f(u0.z), bf2f(u0.w));
    float4 a1 = make_float4(bf2f(u1.x), bf2f(u1.y), bf2f(u1.z), bf2f(u1.w));
    float4 b0 = *(const float4*)(w_out + (size_t)(k0 + bk) * DIM + n0 + bc);
    float4 b1 = *(const float4*)(w_out + (size_t)(k0 + bk + 16) * DIM + n0 + bc);
    __syncthreads();
    As[ac + 0][ar] = a0.x; As[ac + 1][ar] = a0.y; As[ac + 2][ar] = a0.z; As[ac + 3][ar] = a0.w;
    As[ac + 0][ar + 32] = a1.x; As[ac + 1][ar + 32] = a1.y; As[ac + 2][ar + 32] = a1.z; As[ac + 3][ar + 32] = a1.w;
    *(float4*)&Bs[bk][bc] = b0;
    *(float4*)&Bs[bk + 16][bc] = b1;
    __syncthreads();
    #pragma unroll
    for (int kk = 0; kk < 32; ++kk) {
      const float4 av = *(const float4*)&As[kk][rb];
      const float4 bv = *(const float4*)&Bs[kk][cb];
      acc[0][0] += av.x * bv.x; acc[0][1] += av.x * bv.y; acc[0][2] += av.x * bv.z; acc[0][3] += av.x * bv.w;
      acc[1][0] += av.y * bv.x; acc[1][1] += av.y * bv.y; acc[1][2] += av.y * bv.z; acc[1][3] += av.y * bv.w;
      acc[2][0] += av.z * bv.x; acc[2][1] += av.z * bv.y; acc[2][2] += av.z * bv.z; acc[2][3] += av.z * bv.w;
      acc[3][0] += av.w * bv.x; acc[3][1] += av.w * bv.y; acc[3][2] += av.w * bv.z; acc[3][3] += av.w * bv.w;
    }
  }
  #pragma unroll
  for (int i = 0; i < 4; ++i) {
    const size_t m = m0 + rb + i;
    #pragma unroll
    for (int j = 0; j < 4; ++j) {
      const int n = n0 + cb + j;
      // xs lives in d_out: read-then-overwrite of the same element by the same thread
      out[m * DIM + n] = acc[i][j] * bf2f(xg[m * HIDD + n]) + xs[m * DIM + n];
    }
  }
}

extern "C" void kernel_launch(void* const* d_in, const int* in_sizes, int n_in,
                              void* d_out, int out_size, void* d_ws, size_t ws_size,
                              hipStream_t stream) {
  const float* x        = (const float*)d_in[0];
  const float* lg       = (const float*)d_in[1];
  const float* lb       = (const float*)d_in[2];
  const float* w_qk     = (const float*)d_in[3];
  const float* g4       = (const float*)d_in[4];
  const float* b4       = (const float*)d_in[5];
  const float* g2       = (const float*)d_in[6];
  const float* b2       = (const float*)d_in[7];
  const float* w_hidden = (const float*)d_in[8];
  const float* w_gate   = (const float*)d_in[9];
  const float* w_out    = (const float*)d_in[10];
  // workspace layout (bytes), total 251,723,776 (~240 MiB):
  //   QK   f32  @ 0           16,777,216
  //   QM   f32  @ 16,777,216      65,536
  //   HID  bf16 @ 16,842,752  33,554,432
  //   GATE bf16 @ 50,397,184  33,554,432
  //   XG   bf16 @ 83,951,616  33,554,432
  //   OUT4 bf16 @ 117,506,048 134,217,728
  // xs (f32, 64 MiB) lives in d_out and is overwritten in-place by k_gemm2.
  if (ws_size < 251723776ull) return;   // graceful fail -> absmax poison, not a GPU fault
  char* ws = (char*)d_ws;
  float* QKb  = (float*)(ws + 0);
  float* QM   = (float*)(ws + 16777216);
  u16*   HID  = (u16*)  (ws + 16842752);
  u16*   GATE = (u16*)  (ws + 50397184);
  u16*   XG   = (u16*)  (ws + 83951616);
  u16*   OUT4 = (u16*)  (ws + 117506048);
  float* XS   = (float*)d_out;
  float* OUT  = (float*)d_out;

  k_ln<<<BB * SEQ, 256, 0, stream>>>(x, lg, lb, XS);
  k_gemm1<<<dim3(512, 26), 256, 0, stream>>>(XS, w_qk, w_hidden, w_gate, QKb, HID, GATE, XG);
  k_qkmean<<<BB * GG, 128, 0, stream>>>(QKb, QM);
  k_attn<<<BB * GG * 4 * 8, 256, 0, stream>>>(QKb, QM, g4, b4, g2, b2, HID, GATE, OUT4);
  k_gemm2<<<dim3(512, 8), 256, 0, stream>>>(HID, OUT4, w_out, XG, XS, OUT);
}

// Round 3
// 2272.704 us; speedup vs baseline: 2.6390x; 2.6390x over previous
//
#include <hip/hip_runtime.h>
#include <hip/hip_bf16.h>
#include <math.h>

#define BB 4
#define SEQ 8192
#define DIM 512
#define GG 32
#define NPG 256
#define QKD 128
#define HIDD 512

typedef unsigned short u16;
typedef unsigned int u32;

using s16x8 = __attribute__((ext_vector_type(8))) short;
using f32x4 = __attribute__((ext_vector_type(4))) float;

__device__ __forceinline__ float bf2f(u16 u) { return __uint_as_float(((u32)u) << 16); }
__device__ __forceinline__ u16 f2bf(float f) {
  u32 b = __float_as_uint(f);
  return (u16)((b + 0x7FFFu + ((b >> 16) & 1u)) >> 16);
}
__device__ __forceinline__ float silu_f(float x) { return x / (1.f + expf(-x)); }

// ---------------- Kernel 1: LayerNorm + global seq-shift scatter ----------------
__global__ __launch_bounds__(256) void k_ln(const float* __restrict__ x,
    const float* __restrict__ lg, const float* __restrict__ lb, float* __restrict__ xs) {
  const int row = blockIdx.x;               // b*SEQ + s
  const int s = row & (SEQ - 1);
  const int t = threadIdx.x;
  const float* xr = x + (size_t)row * DIM;
  float v0 = xr[t], v1 = xr[t + 256];
  float sum = v0 + v1, sq = v0 * v0 + v1 * v1;
  #pragma unroll
  for (int o = 32; o; o >>= 1) { sum += __shfl_down(sum, o); sq += __shfl_down(sq, o); }
  __shared__ float sm[8];
  const int w = t >> 6;
  if ((t & 63) == 0) { sm[w] = sum; sm[4 + w] = sq; }
  __syncthreads();
  if (t == 0) {
    float S = sm[0] + sm[1] + sm[2] + sm[3];
    float Q = sm[4] + sm[5] + sm[6] + sm[7];
    float mu = S * (1.f / DIM);
    float var = Q * (1.f / DIM) - mu * mu;
    sm[0] = mu; sm[4] = rsqrtf(var + 1e-5f);
  }
  __syncthreads();
  const float mu = sm[0], rs = sm[4];
  float y0 = (v0 - mu) * rs * lg[t] + lb[t];
  float y1 = (v1 - mu) * rs * lg[t + 256] + lb[t + 256];
  xs[(size_t)row * DIM + t + 256] = y1;
  if (s + 1 < SEQ) xs[(size_t)(row + 1) * DIM + t] = y0;
  if (s == 0) xs[(size_t)row * DIM + t] = 0.f;
}

// ---------------- Kernel 2: fused GEMM xs @ [w_qk | w_hidden | w_gate] ----------------
// Outputs: qk bf16 [32768][128]; HIDT bf16 [bg][e=512][j=256] (transposed hidden);
//          gate bf16 [32768][512]; xg = silu(xs@w_gate) bf16 [32768][512]
__global__ __launch_bounds__(256) void k_gemm1(const float* __restrict__ xs,
    const float* __restrict__ w_qk, const float* __restrict__ w_hidden,
    const float* __restrict__ w_gate, u16* __restrict__ qk,
    u16* __restrict__ hidt, u16* __restrict__ gate, u16* __restrict__ xg) {
  __shared__ float As[32][68];   // As[kk][r] = A[m0+r][k0+kk]
  __shared__ float Bs[32][68];   // Bs[kk][c] = B[k0+kk][n0+c]
  const int t = threadIdx.x;
  const int m0 = blockIdx.x * 64;
  const int n0 = blockIdx.y * 64;
  const float* bptr; int ld, coff;
  if (n0 < 128)       { bptr = w_qk;     ld = 128;  coff = n0; }
  else if (n0 < 1152) { bptr = w_hidden; ld = 1024; coff = n0 - 128; }
  else                { bptr = w_gate;   ld = 512;  coff = n0 - 1152; }
  float acc[4][4];
  #pragma unroll
  for (int i = 0; i < 4; ++i)
    #pragma unroll
    for (int j = 0; j < 4; ++j) acc[i][j] = 0.f;
  const int ar = t >> 3, ac = (t & 7) << 2;
  const int bk = t >> 4, bc = (t & 15) << 2;
  const int rb = (t >> 4) << 2, cb = (t & 15) << 2;
  for (int k0 = 0; k0 < DIM; k0 += 32) {
    float4 a0 = *(const float4*)(xs + (size_t)(m0 + ar) * DIM + k0 + ac);
    float4 a1 = *(const float4*)(xs + (size_t)(m0 + ar + 32) * DIM + k0 + ac);
    float4 b0 = *(const float4*)(bptr + (size_t)(k0 + bk) * ld + coff + bc);
    float4 b1 = *(const float4*)(bptr + (size_t)(k0 + bk + 16) * ld + coff + bc);
    __syncthreads();
    As[ac + 0][ar] = a0.x; As[ac + 1][ar] = a0.y; As[ac + 2][ar] = a0.z; As[ac + 3][ar] = a0.w;
    As[ac + 0][ar + 32] = a1.x; As[ac + 1][ar + 32] = a1.y; As[ac + 2][ar + 32] = a1.z; As[ac + 3][ar + 32] = a1.w;
    *(float4*)&Bs[bk][bc] = b0;
    *(float4*)&Bs[bk + 16][bc] = b1;
    __syncthreads();
    #pragma unroll
    for (int kk = 0; kk < 32; ++kk) {
      const float4 av = *(const float4*)&As[kk][rb];
      const float4 bv = *(const float4*)&Bs[kk][cb];
      acc[0][0] += av.x * bv.x; acc[0][1] += av.x * bv.y; acc[0][2] += av.x * bv.z; acc[0][3] += av.x * bv.w;
      acc[1][0] += av.y * bv.x; acc[1][1] += av.y * bv.y; acc[1][2] += av.y * bv.z; acc[1][3] += av.y * bv.w;
      acc[2][0] += av.z * bv.x; acc[2][1] += av.z * bv.y; acc[2][2] += av.z * bv.z; acc[2][3] += av.z * bv.w;
      acc[3][0] += av.w * bv.x; acc[3][1] += av.w * bv.y; acc[3][2] += av.w * bv.z; acc[3][3] += av.w * bv.w;
    }
  }
  if (n0 >= 128 && n0 < 640) {
    // hidden segment -> transposed HIDT[bg][e][j]; thread's 4 m are consecutive
    const int bg = m0 >> 8;
    const int jbase = (m0 & 255) + rb;
    #pragma unroll
    for (int jj = 0; jj < 4; ++jj) {
      const int e = n0 - 128 + cb + jj;
      ushort4 pk;
      pk.x = f2bf(acc[0][jj]); pk.y = f2bf(acc[1][jj]);
      pk.z = f2bf(acc[2][jj]); pk.w = f2bf(acc[3][jj]);
      *(ushort4*)(hidt + ((size_t)bg * 512 + e) * 256 + jbase) = pk;
    }
  } else {
    #pragma unroll
    for (int i = 0; i < 4; ++i) {
      const size_t m = m0 + rb + i;
      #pragma unroll
      for (int j = 0; j < 4; ++j) {
        const int n = n0 + cb + j;
        float v = acc[i][j];
        if (n0 < 128)       qk[m * QKD + n] = f2bf(v);
        else if (n0 < 1152) gate[m * HIDD + (n - 640)] = f2bf(v);
        else                xg[m * HIDD + (n - 1152)] = f2bf(silu_f(v));
      }
    }
  }
}

// ---------------- Kernel 3: qk_mean over each group's 256 rows ----------------
__global__ __launch_bounds__(128) void k_qkmean(const u16* __restrict__ qk, float* __restrict__ qm) {
  const int bg = blockIdx.x;
  const int c = threadIdx.x;
  const u16* p = qk + (size_t)bg * NPG * QKD + c;
  float s = 0.f;
  for (int i = 0; i < NPG; ++i) s += bf2f(p[(size_t)i * QKD]);
  qm[(size_t)bg * QKD + c] = s * (1.f / NPG);
}

// ---------------- Kernel 4: MFMA attention per (b,g,h, 64-row block) ----------------
// 4 waves x 16 rows. QK^T + PV via mfma_f32_16x16x32_bf16.
// A layout: lane holds A[row=l&15][k=8*(l>>4)+i]; B: B[k=8*(l>>4)+i][col=l&15];
// C/D: C[row=(l>>4)*4+reg][col=l&15]  (guide-verified).
__global__ __launch_bounds__(256, 2) void k_attn(const u16* __restrict__ qk,
    const float* __restrict__ qm, const float* __restrict__ g4, const float* __restrict__ b4,
    const float* __restrict__ g2, const float* __restrict__ b2,
    const u16* __restrict__ hidt, const u16* __restrict__ gate, u16* __restrict__ out4) {
  __shared__ u16 Ks[256][72];    // K_all[h], padded stride 144B
  __shared__ u16 Qs[64][72];
  __shared__ u16 Pl[64][264];    // P bf16, stride 528B (16B-aligned rows)
  const int t = threadIdx.x;
  const int blk = blockIdx.x;
  const int rb = blk & 3, h = (blk >> 2) & 3, bg = blk >> 4;
  const size_t grpRow = (size_t)bg * NPG;
  const int cbase = (h & 1) << 6;
  // ---- stage K (256x64) and Q (64x64) with affine transforms ----
  const int d = t & 63, ccol = cbase + d;
  const float qmv = qm[(size_t)bg * QKD + ccol];
  const float qof = qmv * g4[ccol] + b4[ccol];
  const float kof = qmv * g4[QKD + ccol] + b4[QKD + ccol];
  const float qsc = qmv * g4[2 * QKD + ccol] + b4[2 * QKD + ccol];
  const float ksc = qmv * g4[3 * QKD + ccol] + b4[3 * QKD + ccol];
  const float qso = qmv * g2[ccol] + b2[ccol];
  const float kso = qmv * g2[QKD + ccol] + b2[QKD + ccol];
  for (int j = t >> 6; j < NPG; j += 4) {
    float kv;
    if (h < 2) kv = bf2f(qk[(grpRow + j) * QKD + ccol]) * ksc + kof;
    else {
      float prev = j ? (bf2f(qk[(grpRow + j - 1) * QKD + ccol]) * ksc + kof) : 0.f;
      kv = prev * ksc + kso;
    }
    Ks[j][d] = f2bf(kv);
  }
  for (int i = t >> 6; i < 64; i += 4) {
    int gi = rb * 64 + i;
    float qv;
    if (h < 2) qv = bf2f(qk[(grpRow + gi) * QKD + ccol]) * qsc + qof;
    else {
      float prev = gi ? (bf2f(qk[(grpRow + gi - 1) * QKD + ccol]) * qsc + qof) : 0.f;
      qv = prev * qsc + qso;
    }
    Qs[i][d] = f2bf(qv);
  }
  __syncthreads();
  // ---- per-wave independent from here ----
  const int w = t >> 6, l = t & 63;
  const int lr = l & 15, lq = l >> 4;
  // QK^T: full 16 col-tiles (cheap), mask later
  s16x8 qa0 = *(const s16x8*)&Qs[w * 16 + lr][8 * lq];
  s16x8 qa1 = *(const s16x8*)&Qs[w * 16 + lr][32 + 8 * lq];
  f32x4 sfr[16];
  #pragma unroll
  for (int nt = 0; nt < 16; ++nt) {
    s16x8 kb0 = *(const s16x8*)&Ks[nt * 16 + lr][8 * lq];
    s16x8 kb1 = *(const s16x8*)&Ks[nt * 16 + lr][32 + 8 * lq];
    f32x4 c = {0.f, 0.f, 0.f, 0.f};
    c = __builtin_amdgcn_mfma_f32_16x16x32_bf16(qa0, kb0, c, 0, 0, 0);
    c = __builtin_amdgcn_mfma_f32_16x16x32_bf16(qa1, kb1, c, 0, 0, 0);
    sfr[nt] = c;
  }
  // ---- causal softmax on 4 rows (rowb..rowb+3), cols spread over 16-lane group ----
  const float scl = 0.17677669529663687f;   // 1/sqrt(32)
  const int rowb = rb * 64 + w * 16 + lq * 4;
  float m0 = -3.4e38f, m1 = -3.4e38f, m2 = -3.4e38f, m3 = -3.4e38f;
  #pragma unroll
  for (int nt = 0; nt < 16; ++nt) {
    int col = nt * 16 + lr;
    f32x4 c = sfr[nt];
    if (col <= rowb + 0) m0 = fmaxf(m0, c[0] * scl);
    if (col <= rowb + 1) m1 = fmaxf(m1, c[1] * scl);
    if (col <= rowb + 2) m2 = fmaxf(m2, c[2] * scl);
    if (col <= rowb + 3) m3 = fmaxf(m3, c[3] * scl);
  }
  #pragma unroll
  for (int o = 1; o < 16; o <<= 1) {
    m0 = fmaxf(m0, __shfl_xor(m0, o)); m1 = fmaxf(m1, __shfl_xor(m1, o));
    m2 = fmaxf(m2, __shfl_xor(m2, o)); m3 = fmaxf(m3, __shfl_xor(m3, o));
  }
  float s0 = 0.f, s1 = 0.f, s2 = 0.f, s3 = 0.f;
  #pragma unroll
  for (int nt = 0; nt < 16; ++nt) {
    int col = nt * 16 + lr;
    f32x4 c = sfr[nt];
    float e0 = (col <= rowb + 0) ? expf(c[0] * scl - m0) : 0.f;
    float e1 = (col <= rowb + 1) ? expf(c[1] * scl - m1) : 0.f;
    float e2 = (col <= rowb + 2) ? expf(c[2] * scl - m2) : 0.f;
    float e3 = (col <= rowb + 3) ? expf(c[3] * scl - m3) : 0.f;
    s0 += e0; s1 += e1; s2 += e2; s3 += e3;
    c[0] = e0; c[1] = e1; c[2] = e2; c[3] = e3;
    sfr[nt] = c;
  }
  #pragma unroll
  for (int o = 1; o < 16; o <<= 1) {
    s0 += __shfl_xor(s0, o); s1 += __shfl_xor(s1, o);
    s2 += __shfl_xor(s2, o); s3 += __shfl_xor(s3, o);
  }
  const float i0 = 1.f / s0, i1 = 1.f / s1, i2 = 1.f / s2, i3 = 1.f / s3;
  #pragma unroll
  for (int nt = 0; nt < 16; ++nt) {
    f32x4 c = sfr[nt];
    Pl[w * 16 + lq * 4 + 0][nt * 16 + lr] = f2bf(c[0] * i0);
    Pl[w * 16 + lq * 4 + 1][nt * 16 + lr] = f2bf(c[1] * i1);
    Pl[w * 16 + lq * 4 + 2][nt * 16 + lr] = f2bf(c[2] * i2);
    Pl[w * 16 + lq * 4 + 3][nt * 16 + lr] = f2bf(c[3] * i3);
  }
  // ---- PV: A = P (LDS), B = V from HIDT[bg][e][j] (global, j-contiguous) ----
  const u16* vt = hidt + (size_t)bg * (512 * 256);
  const int jtmax = (rb * 4 + w) >> 1;          // causal j-tile bound (32 j per tile)
  for (int half = 0; half < 2; ++half) {
    f32x4 acc[16];
    #pragma unroll
    for (int nt = 0; nt < 16; ++nt) acc[nt] = (f32x4){0.f, 0.f, 0.f, 0.f};
    #pragma unroll
    for (int jt = 0; jt < 8; ++jt) {
      if (jt <= jtmax) {
        s16x8 pa = *(const s16x8*)&Pl[w * 16 + lr][jt * 32 + 8 * lq];
        #pragma unroll
        for (int nt = 0; nt < 16; ++nt) {
          const size_t e = half * 256 + nt * 16 + lr;
          s16x8 vb = *(const s16x8*)(vt + e * 256 + jt * 32 + 8 * lq);
          acc[nt] = __builtin_amdgcn_mfma_f32_16x16x32_bf16(pa, vb, acc[nt], 0, 0, 0);
        }
      }
    }
    // epilogue: silu(out) * gate -> out4[srow][h*512 + e]
    #pragma unroll
    for (int nt = 0; nt < 16; ++nt) {
      const int e = half * 256 + nt * 16 + lr;
      #pragma unroll
      for (int r = 0; r < 4; ++r) {
        const size_t srow = grpRow + rowb + r;
        float g = bf2f(gate[srow * HIDD + e]);
        out4[srow * 2048 + (h << 9) + e] = f2bf(silu_f(acc[nt][r]) * g);
      }
    }
  }
}

// ---------------- Kernel 5: final GEMM residual(2560) @ w_out + epilogue ----------------
// A k<512 segment read from transposed HIDT (B-style staging); k>=512 from out4 rows.
__global__ __launch_bounds__(256) void k_gemm2(const u16* __restrict__ hidt,
    const u16* __restrict__ out4, const float* __restrict__ w_out,
    const u16* __restrict__ xg, const float* __restrict__ xs, float* __restrict__ out) {
  __shared__ float As[32][68];
  __shared__ float Bs[32][68];
  const int t = threadIdx.x;
  const int m0 = blockIdx.x * 64, n0 = blockIdx.y * 64;
  float acc[4][4];
  #pragma unroll
  for (int i = 0; i < 4; ++i)
    #pragma unroll
    for (int j = 0; j < 4; ++j) acc[i][j] = 0.f;
  const int ar = t >> 3, ac = (t & 7) << 2;
  const int bk = t >> 4, bc = (t & 15) << 2;
  const int rb = (t >> 4) << 2, cb = (t & 15) << 2;
  const int bg = m0 >> 8, jb = m0 & 255;
  for (int k0 = 0; k0 < 2560; k0 += 32) {
    float4 a0, a1;
    if (k0 < 512) {
      // As[kk][r] = HIDT[bg][k0+kk][jb + r]  (coalesced in j)
      ushort4 h0 = *(const ushort4*)(hidt + ((size_t)bg * 512 + k0 + bk) * 256 + jb + bc);
      ushort4 h1 = *(const ushort4*)(hidt + ((size_t)bg * 512 + k0 + bk + 16) * 256 + jb + bc);
      a0 = make_float4(bf2f(h0.x), bf2f(h0.y), bf2f(h0.z), bf2f(h0.w));
      a1 = make_float4(bf2f(h1.x), bf2f(h1.y), bf2f(h1.z), bf2f(h1.w));
    } else {
      ushort4 u0 = *(const ushort4*)(out4 + (size_t)(m0 + ar) * 2048 + (k0 - 512) + ac);
      ushort4 u1 = *(const ushort4*)(out4 + (size_t)(m0 + ar + 32) * 2048 + (k0 - 512) + ac);
      a0 = make_float4(bf2f(u0.x), bf2f(u0.y), bf2f(u0.z), bf2f(u0.w));
      a1 = make_float4(bf2f(u1.x), bf2f(u1.y), bf2f(u1.z), bf2f(u1.w));
    }
    float4 b0 = *(const float4*)(w_out + (size_t)(k0 + bk) * DIM + n0 + bc);
    float4 b1 = *(const float4*)(w_out + (size_t)(k0 + bk + 16) * DIM + n0 + bc);
    __syncthreads();
    if (k0 < 512) {
      *(float4*)&As[bk][bc] = a0;
      *(float4*)&As[bk + 16][bc] = a1;
    } else {
      As[ac + 0][ar] = a0.x; As[ac + 1][ar] = a0.y; As[ac + 2][ar] = a0.z; As[ac + 3][ar] = a0.w;
      As[ac + 0][ar + 32] = a1.x; As[ac + 1][ar + 32] = a1.y; As[ac + 2][ar + 32] = a1.z; As[ac + 3][ar + 32] = a1.w;
    }
    *(float4*)&Bs[bk][bc] = b0;
    *(float4*)&Bs[bk + 16][bc] = b1;
    __syncthreads();
    #pragma unroll
    for (int kk = 0; kk < 32; ++kk) {
      const float4 av = *(const float4*)&As[kk][rb];
      const float4 bv = *(const float4*)&Bs[kk][cb];
      acc[0][0] += av.x * bv.x; acc[0][1] += av.x * bv.y; acc[0][2] += av.x * bv.z; acc[0][3] += av.x * bv.w;
      acc[1][0] += av.y * bv.x; acc[1][1] += av.y * bv.y; acc[1][2] += av.y * bv.z; acc[1][3] += av.y * bv.w;
      acc[2][0] += av.z * bv.x; acc[2][1] += av.z * bv.y; acc[2][2] += av.z * bv.z; acc[2][3] += av.z * bv.w;
      acc[3][0] += av.w * bv.x; acc[3][1] += av.w * bv.y; acc[3][2] += av.w * bv.z; acc[3][3] += av.w * bv.w;
    }
  }
  #pragma unroll
  for (int i = 0; i < 4; ++i) {
    const size_t m = m0 + rb + i;
    #pragma unroll
    for (int j = 0; j < 4; ++j) {
      const int n = n0 + cb + j;
      out[m * DIM + n] = acc[i][j] * bf2f(xg[m * HIDD + n]) + xs[m * DIM + n];
    }
  }
}

extern "C" void kernel_launch(void* const* d_in, const int* in_sizes, int n_in,
                              void* d_out, int out_size, void* d_ws, size_t ws_size,
                              hipStream_t stream) {
  const float* x        = (const float*)d_in[0];
  const float* lg       = (const float*)d_in[1];
  const float* lb       = (const float*)d_in[2];
  const float* w_qk     = (const float*)d_in[3];
  const float* g4       = (const float*)d_in[4];
  const float* b4       = (const float*)d_in[5];
  const float* g2       = (const float*)d_in[6];
  const float* b2       = (const float*)d_in[7];
  const float* w_hidden = (const float*)d_in[8];
  const float* w_gate   = (const float*)d_in[9];
  const float* w_out    = (const float*)d_in[10];
  // ws layout (bytes), total 243,335,168 (~232 MiB):
  //   QK   bf16 @ 0            8,388,608
  //   QM   f32  @ 8,388,608       65,536
  //   HIDT bf16 @ 8,454,144   33,554,432   [bg][e=512][j=256]
  //   GATE bf16 @ 42,008,576  33,554,432
  //   XG   bf16 @ 75,563,008  33,554,432
  //   OUT4 bf16 @ 109,117,440 134,217,728
  // xs (f32, 64 MiB) lives in d_out, overwritten in-place by k_gemm2 epilogue.
  if (ws_size < 243335168ull) return;
  char* ws = (char*)d_ws;
  u16*   QKb  = (u16*)  (ws + 0);
  float* QM   = (float*)(ws + 8388608);
  u16*   HIDT = (u16*)  (ws + 8454144);
  u16*   GATE = (u16*)  (ws + 42008576);
  u16*   XG   = (u16*)  (ws + 75563008);
  u16*   OUT4 = (u16*)  (ws + 109117440);
  float* XS   = (float*)d_out;
  float* OUT  = (float*)d_out;

  k_ln<<<BB * SEQ, 256, 0, stream>>>(x, lg, lb, XS);
  k_gemm1<<<dim3(512, 26), 256, 0, stream>>>(XS, w_qk, w_hidden, w_gate, QKb, HIDT, GATE, XG);
  k_qkmean<<<BB * GG, 128, 0, stream>>>(QKb, QM);
  k_attn<<<BB * GG * 4 * 4, 256, 0, stream>>>(QKb, QM, g4, b4, g2, b2, HIDT, GATE, OUT4);
  k_gemm2<<<dim3(512, 8), 256, 0, stream>>>(HIDT, OUT4, w_out, XG, XS, OUT);
}

// Round 4
// 683.461 us; speedup vs baseline: 8.7754x; 3.3253x over previous
//
#include <hip/hip_runtime.h>
#include <hip/hip_bf16.h>
#include <math.h>

#define BB 4
#define SEQ 8192
#define DIM 512
#define GG 32
#define NPG 256
#define QKD 128
#define HIDD 512

typedef unsigned short u16;
typedef unsigned int u32;

using s16x8 = __attribute__((ext_vector_type(8))) short;
using f32x4 = __attribute__((ext_vector_type(4))) float;

__device__ __forceinline__ float bf2f(u16 u) { return __uint_as_float(((u32)u) << 16); }
__device__ __forceinline__ u16 f2bf(float f) {
  u32 b = __float_as_uint(f);
  return (u16)((b + 0x7FFFu + ((b >> 16) & 1u)) >> 16);
}
__device__ __forceinline__ float silu_f(float x) { return x / (1.f + expf(-x)); }

// ---------------- Kernel 1: LayerNorm + global seq-shift scatter ----------------
__global__ __launch_bounds__(256) void k_ln(const float* __restrict__ x,
    const float* __restrict__ lg, const float* __restrict__ lb, float* __restrict__ xs) {
  const int row = blockIdx.x;               // b*SEQ + s
  const int s = row & (SEQ - 1);
  const int t = threadIdx.x;
  const float* xr = x + (size_t)row * DIM;
  float v0 = xr[t], v1 = xr[t + 256];
  float sum = v0 + v1, sq = v0 * v0 + v1 * v1;
  #pragma unroll
  for (int o = 32; o; o >>= 1) { sum += __shfl_down(sum, o); sq += __shfl_down(sq, o); }
  __shared__ float sm[8];
  const int w = t >> 6;
  if ((t & 63) == 0) { sm[w] = sum; sm[4 + w] = sq; }
  __syncthreads();
  if (t == 0) {
    float S = sm[0] + sm[1] + sm[2] + sm[3];
    float Q = sm[4] + sm[5] + sm[6] + sm[7];
    float mu = S * (1.f / DIM);
    float var = Q * (1.f / DIM) - mu * mu;
    sm[0] = mu; sm[4] = rsqrtf(var + 1e-5f);
  }
  __syncthreads();
  const float mu = sm[0], rs = sm[4];
  float y0 = (v0 - mu) * rs * lg[t] + lb[t];
  float y1 = (v1 - mu) * rs * lg[t + 256] + lb[t + 256];
  xs[(size_t)row * DIM + t + 256] = y1;
  if (s + 1 < SEQ) xs[(size_t)(row + 1) * DIM + t] = y0;
  if (s == 0) xs[(size_t)row * DIM + t] = 0.f;
}

// ---------------- weight transpose f32 [K][N] -> bf16 [rowOff+n][dstLD] ----------------
__global__ __launch_bounds__(256) void k_trw(const float* __restrict__ src, u16* __restrict__ dst,
    int N, int dstLD, int rowOff) {
  __shared__ u16 T[64][66];
  const int t = threadIdx.x;
  const int k0 = blockIdx.x * 64, n0 = blockIdx.y * 64;
  #pragma unroll
  for (int i = 0; i < 16; ++i) {
    int idx = t + 256 * i;
    int r = idx >> 6, c = idx & 63;            // r: k-dir, c: n-dir
    T[c][r] = f2bf(src[(size_t)(k0 + r) * N + n0 + c]);
  }
  __syncthreads();
  #pragma unroll
  for (int i = 0; i < 16; ++i) {
    int idx = t + 256 * i;
    int r = idx >> 6, c = idx & 63;            // r: n-dir, c: k-dir
    dst[(size_t)(rowOff + n0 + r) * dstLD + k0 + c] = T[r][c];
  }
}

// ---------------- HIDT [bg][e=512][j=256] -> HIDR [bg*256+j][512] (bf16) ----------------
__global__ __launch_bounds__(256) void k_trh(const u16* __restrict__ hidt, u16* __restrict__ hidr) {
  __shared__ u16 T[64][66];
  const int t = threadIdx.x;
  const int j0 = blockIdx.x * 64;
  const int e0 = blockIdx.y * 64;
  const int bg = blockIdx.z;
  #pragma unroll
  for (int i = 0; i < 16; ++i) {
    int idx = t + 256 * i; int r = idx >> 6, c = idx & 63;   // r: e, c: j
    T[c][r] = hidt[((size_t)bg * 512 + e0 + r) * 256 + j0 + c];
  }
  __syncthreads();
  #pragma unroll
  for (int i = 0; i < 16; ++i) {
    int idx = t + 256 * i; int r = idx >> 6, c = idx & 63;   // r: j, c: e
    hidr[((size_t)bg * 256 + j0 + r) * 512 + e0 + c] = T[r][c];
  }
}

// ---------------- Kernel 2: MFMA GEMM xs @ [w_qk | w_hidden | w_gate] ----------------
// A = xs f32 [32768][512] (converted to bf16 in staging); B = W1T bf16 [1664][512] (n-major, k-contig).
// n segments: [0,128) qk | [128,640) hidden->HIDT | [640,1152) gate | [1152,1664) silu->xg
__global__ __launch_bounds__(256, 2) void k_gemm1m(const float* __restrict__ xs,
    const u16* __restrict__ w1t, u16* __restrict__ qk, u16* __restrict__ hidt,
    u16* __restrict__ gate, u16* __restrict__ xg) {
  __shared__ u16 As[128][72];
  __shared__ u16 Bs[128][72];
  const int t = threadIdx.x;
  const int m0 = blockIdx.x * 128, n0 = blockIdx.y * 128;
  const int w = t >> 6, l = t & 63, lr = l & 15, lq = l >> 4;
  const int wr = (w >> 1) * 64, wc = (w & 1) * 64;
  const int sr = t >> 3;            // 0..31 staging row
  const int sk = (t & 7) * 8;       // staging k elem offset
  f32x4 acc[4][4];
  #pragma unroll
  for (int i = 0; i < 4; ++i)
    #pragma unroll
    for (int j = 0; j < 4; ++j) acc[i][j] = (f32x4){0.f, 0.f, 0.f, 0.f};
  for (int k0 = 0; k0 < 512; k0 += 64) {
    s16x8 aS[4], bS[4];
    #pragma unroll
    for (int it = 0; it < 4; ++it) {
      const float* ap = xs + (size_t)(m0 + sr + it * 32) * 512 + k0 + sk;
      float4 f0 = *(const float4*)ap;
      float4 f1 = *(const float4*)(ap + 4);
      s16x8 v;
      v[0] = (short)f2bf(f0.x); v[1] = (short)f2bf(f0.y); v[2] = (short)f2bf(f0.z); v[3] = (short)f2bf(f0.w);
      v[4] = (short)f2bf(f1.x); v[5] = (short)f2bf(f1.y); v[6] = (short)f2bf(f1.z); v[7] = (short)f2bf(f1.w);
      aS[it] = v;
      bS[it] = *(const s16x8*)(w1t + (size_t)(n0 + sr + it * 32) * 512 + k0 + sk);
    }
    __syncthreads();
    #pragma unroll
    for (int it = 0; it < 4; ++it) {
      *(s16x8*)&As[sr + it * 32][sk] = aS[it];
      *(s16x8*)&Bs[sr + it * 32][sk] = bS[it];
    }
    __syncthreads();
    #pragma unroll
    for (int kk = 0; kk < 64; kk += 32) {
      s16x8 af[4], bf[4];
      #pragma unroll
      for (int fi = 0; fi < 4; ++fi) af[fi] = *(const s16x8*)&As[wr + fi * 16 + lr][kk + 8 * lq];
      #pragma unroll
      for (int fj = 0; fj < 4; ++fj) bf[fj] = *(const s16x8*)&Bs[wc + fj * 16 + lr][kk + 8 * lq];
      #pragma unroll
      for (int fi = 0; fi < 4; ++fi)
        #pragma unroll
        for (int fj = 0; fj < 4; ++fj)
          acc[fi][fj] = __builtin_amdgcn_mfma_f32_16x16x32_bf16(af[fi], bf[fj], acc[fi][fj], 0, 0, 0);
    }
  }
  // epilogue (segment is block-uniform: boundaries are 128-aligned)
  if (n0 == 0) {
    #pragma unroll
    for (int fi = 0; fi < 4; ++fi)
      #pragma unroll
      for (int fj = 0; fj < 4; ++fj) {
        const int n = wc + fj * 16 + lr;
        const int mb = m0 + wr + fi * 16 + lq * 4;
        #pragma unroll
        for (int r = 0; r < 4; ++r)
          qk[(size_t)(mb + r) * QKD + n] = f2bf(acc[fi][fj][r]);
      }
  } else if (n0 < 640) {
    const int bg = m0 >> 8;
    #pragma unroll
    for (int fi = 0; fi < 4; ++fi)
      #pragma unroll
      for (int fj = 0; fj < 4; ++fj) {
        const int e = n0 - 128 + wc + fj * 16 + lr;
        const int j0 = (m0 & 255) + wr + fi * 16 + lq * 4;
        ushort4 pk;
        pk.x = f2bf(acc[fi][fj][0]); pk.y = f2bf(acc[fi][fj][1]);
        pk.z = f2bf(acc[fi][fj][2]); pk.w = f2bf(acc[fi][fj][3]);
        *(ushort4*)(hidt + ((size_t)bg * 512 + e) * 256 + j0) = pk;
      }
  } else if (n0 < 1152) {
    #pragma unroll
    for (int fi = 0; fi < 4; ++fi)
      #pragma unroll
      for (int fj = 0; fj < 4; ++fj) {
        const int n = n0 - 640 + wc + fj * 16 + lr;
        const int mb = m0 + wr + fi * 16 + lq * 4;
        #pragma unroll
        for (int r = 0; r < 4; ++r)
          gate[(size_t)(mb + r) * HIDD + n] = f2bf(acc[fi][fj][r]);
      }
  } else {
    #pragma unroll
    for (int fi = 0; fi < 4; ++fi)
      #pragma unroll
      for (int fj = 0; fj < 4; ++fj) {
        const int n = n0 - 1152 + wc + fj * 16 + lr;
        const int mb = m0 + wr + fi * 16 + lq * 4;
        #pragma unroll
        for (int r = 0; r < 4; ++r)
          xg[(size_t)(mb + r) * HIDD + n] = f2bf(silu_f(acc[fi][fj][r]));
      }
  }
}

// ---------------- Kernel 3: qk_mean over each group's 256 rows ----------------
__global__ __launch_bounds__(128) void k_qkmean(const u16* __restrict__ qk, float* __restrict__ qm) {
  const int bg = blockIdx.x;
  const int c = threadIdx.x;
  const u16* p = qk + (size_t)bg * NPG * QKD + c;
  float s = 0.f;
  for (int i = 0; i < NPG; ++i) s += bf2f(p[(size_t)i * QKD]);
  qm[(size_t)bg * QKD + c] = s * (1.f / NPG);
}

// ---------------- Kernel 4: MFMA attention per (b,g,h, 64-row block) ----------------
__global__ __launch_bounds__(256, 2) void k_attn(const u16* __restrict__ qk,
    const float* __restrict__ qm, const float* __restrict__ g4, const float* __restrict__ b4,
    const float* __restrict__ g2, const float* __restrict__ b2,
    const u16* __restrict__ hidt, const u16* __restrict__ gate, u16* __restrict__ out4) {
  __shared__ u16 Ks[256][72];
  __shared__ u16 Qs[64][72];
  __shared__ u16 Pl[64][264];
  const int t = threadIdx.x;
  const int blk = blockIdx.x;
  const int rb = blk & 3, h = (blk >> 2) & 3, bg = blk >> 4;
  const size_t grpRow = (size_t)bg * NPG;
  const int cbase = (h & 1) << 6;
  const int d = t & 63, ccol = cbase + d;
  const float qmv = qm[(size_t)bg * QKD + ccol];
  const float qof = qmv * g4[ccol] + b4[ccol];
  const float kof = qmv * g4[QKD + ccol] + b4[QKD + ccol];
  const float qsc = qmv * g4[2 * QKD + ccol] + b4[2 * QKD + ccol];
  const float ksc = qmv * g4[3 * QKD + ccol] + b4[3 * QKD + ccol];
  const float qso = qmv * g2[ccol] + b2[ccol];
  const float kso = qmv * g2[QKD + ccol] + b2[QKD + ccol];
  for (int j = t >> 6; j < NPG; j += 4) {
    float kv;
    if (h < 2) kv = bf2f(qk[(grpRow + j) * QKD + ccol]) * ksc + kof;
    else {
      float prev = j ? (bf2f(qk[(grpRow + j - 1) * QKD + ccol]) * ksc + kof) : 0.f;
      kv = prev * ksc + kso;
    }
    Ks[j][d] = f2bf(kv);
  }
  for (int i = t >> 6; i < 64; i += 4) {
    int gi = rb * 64 + i;
    float qv;
    if (h < 2) qv = bf2f(qk[(grpRow + gi) * QKD + ccol]) * qsc + qof;
    else {
      float prev = gi ? (bf2f(qk[(grpRow + gi - 1) * QKD + ccol]) * qsc + qof) : 0.f;
      qv = prev * qsc + qso;
    }
    Qs[i][d] = f2bf(qv);
  }
  __syncthreads();
  const int w = t >> 6, l = t & 63;
  const int lr = l & 15, lq = l >> 4;
  s16x8 qa0 = *(const s16x8*)&Qs[w * 16 + lr][8 * lq];
  s16x8 qa1 = *(const s16x8*)&Qs[w * 16 + lr][32 + 8 * lq];
  f32x4 sfr[16];
  #pragma unroll
  for (int nt = 0; nt < 16; ++nt) {
    s16x8 kb0 = *(const s16x8*)&Ks[nt * 16 + lr][8 * lq];
    s16x8 kb1 = *(const s16x8*)&Ks[nt * 16 + lr][32 + 8 * lq];
    f32x4 c = {0.f, 0.f, 0.f, 0.f};
    c = __builtin_amdgcn_mfma_f32_16x16x32_bf16(qa0, kb0, c, 0, 0, 0);
    c = __builtin_amdgcn_mfma_f32_16x16x32_bf16(qa1, kb1, c, 0, 0, 0);
    sfr[nt] = c;
  }
  const float scl = 0.17677669529663687f;
  const int rowb = rb * 64 + w * 16 + lq * 4;
  float m0 = -3.4e38f, m1 = -3.4e38f, m2 = -3.4e38f, m3 = -3.4e38f;
  #pragma unroll
  for (int nt = 0; nt < 16; ++nt) {
    int col = nt * 16 + lr;
    f32x4 c = sfr[nt];
    if (col <= rowb + 0) m0 = fmaxf(m0, c[0] * scl);
    if (col <= rowb + 1) m1 = fmaxf(m1, c[1] * scl);
    if (col <= rowb + 2) m2 = fmaxf(m2, c[2] * scl);
    if (col <= rowb + 3) m3 = fmaxf(m3, c[3] * scl);
  }
  #pragma unroll
  for (int o = 1; o < 16; o <<= 1) {
    m0 = fmaxf(m0, __shfl_xor(m0, o)); m1 = fmaxf(m1, __shfl_xor(m1, o));
    m2 = fmaxf(m2, __shfl_xor(m2, o)); m3 = fmaxf(m3, __shfl_xor(m3, o));
  }
  float s0 = 0.f, s1 = 0.f, s2 = 0.f, s3 = 0.f;
  #pragma unroll
  for (int nt = 0; nt < 16; ++nt) {
    int col = nt * 16 + lr;
    f32x4 c = sfr[nt];
    float e0 = (col <= rowb + 0) ? expf(c[0] * scl - m0) : 0.f;
    float e1 = (col <= rowb + 1) ? expf(c[1] * scl - m1) : 0.f;
    float e2 = (col <= rowb + 2) ? expf(c[2] * scl - m2) : 0.f;
    float e3 = (col <= rowb + 3) ? expf(c[3] * scl - m3) : 0.f;
    s0 += e0; s1 += e1; s2 += e2; s3 += e3;
    c[0] = e0; c[1] = e1; c[2] = e2; c[3] = e3;
    sfr[nt] = c;
  }
  #pragma unroll
  for (int o = 1; o < 16; o <<= 1) {
    s0 += __shfl_xor(s0, o); s1 += __shfl_xor(s1, o);
    s2 += __shfl_xor(s2, o); s3 += __shfl_xor(s3, o);
  }
  const float i0 = 1.f / s0, i1 = 1.f / s1, i2 = 1.f / s2, i3 = 1.f / s3;
  #pragma unroll
  for (int nt = 0; nt < 16; ++nt) {
    f32x4 c = sfr[nt];
    Pl[w * 16 + lq * 4 + 0][nt * 16 + lr] = f2bf(c[0] * i0);
    Pl[w * 16 + lq * 4 + 1][nt * 16 + lr] = f2bf(c[1] * i1);
    Pl[w * 16 + lq * 4 + 2][nt * 16 + lr] = f2bf(c[2] * i2);
    Pl[w * 16 + lq * 4 + 3][nt * 16 + lr] = f2bf(c[3] * i3);
  }
  const u16* vt = hidt + (size_t)bg * (512 * 256);
  const int jtmax = (rb * 4 + w) >> 1;
  for (int half = 0; half < 2; ++half) {
    f32x4 acc[16];
    #pragma unroll
    for (int nt = 0; nt < 16; ++nt) acc[nt] = (f32x4){0.f, 0.f, 0.f, 0.f};
    #pragma unroll
    for (int jt = 0; jt < 8; ++jt) {
      if (jt <= jtmax) {
        s16x8 pa = *(const s16x8*)&Pl[w * 16 + lr][jt * 32 + 8 * lq];
        #pragma unroll
        for (int nt = 0; nt < 16; ++nt) {
          const size_t e = half * 256 + nt * 16 + lr;
          s16x8 vb = *(const s16x8*)(vt + e * 256 + jt * 32 + 8 * lq);
          acc[nt] = __builtin_amdgcn_mfma_f32_16x16x32_bf16(pa, vb, acc[nt], 0, 0, 0);
        }
      }
    }
    #pragma unroll
    for (int nt = 0; nt < 16; ++nt) {
      const int e = half * 256 + nt * 16 + lr;
      #pragma unroll
      for (int r = 0; r < 4; ++r) {
        const size_t srow = grpRow + rowb + r;
        float g = bf2f(gate[srow * HIDD + e]);
        out4[srow * 2048 + (h << 9) + e] = f2bf(silu_f(acc[nt][r]) * g);
      }
    }
  }
}

// ---------------- Kernel 5: MFMA GEMM residual(2560) @ w_out + epilogue ----------------
// A: k<512 from HIDR bf16 [m][512]; k>=512 from OUT4 bf16 [m][2048]. B: WT bf16 [512][2560].
__global__ __launch_bounds__(256, 2) void k_gemm2m(const u16* __restrict__ hidr,
    const u16* __restrict__ out4, const u16* __restrict__ wt,
    const u16* __restrict__ xg, float* __restrict__ out) {
  __shared__ u16 As[128][72];
  __shared__ u16 Bs[128][72];
  const int t = threadIdx.x;
  const int m0 = blockIdx.x * 128, n0 = blockIdx.y * 128;
  const int w = t >> 6, l = t & 63, lr = l & 15, lq = l >> 4;
  const int wr = (w >> 1) * 64, wc = (w & 1) * 64;
  const int sr = t >> 3;
  const int sk = (t & 7) * 8;
  f32x4 acc[4][4];
  #pragma unroll
  for (int i = 0; i < 4; ++i)
    #pragma unroll
    for (int j = 0; j < 4; ++j) acc[i][j] = (f32x4){0.f, 0.f, 0.f, 0.f};
  for (int k0 = 0; k0 < 2560; k0 += 64) {
    const u16* abase; size_t ald; int koff;
    if (k0 < 512) { abase = hidr; ald = 512; koff = k0; }
    else          { abase = out4; ald = 2048; koff = k0 - 512; }
    s16x8 aS[4], bS[4];
    #pragma unroll
    for (int it = 0; it < 4; ++it) {
      aS[it] = *(const s16x8*)(abase + (size_t)(m0 + sr + it * 32) * ald + koff + sk);
      bS[it] = *(const s16x8*)(wt + (size_t)(n0 + sr + it * 32) * 2560 + k0 + sk);
    }
    __syncthreads();
    #pragma unroll
    for (int it = 0; it < 4; ++it) {
      *(s16x8*)&As[sr + it * 32][sk] = aS[it];
      *(s16x8*)&Bs[sr + it * 32][sk] = bS[it];
    }
    __syncthreads();
    #pragma unroll
    for (int kk = 0; kk < 64; kk += 32) {
      s16x8 af[4], bf[4];
      #pragma unroll
      for (int fi = 0; fi < 4; ++fi) af[fi] = *(const s16x8*)&As[wr + fi * 16 + lr][kk + 8 * lq];
      #pragma unroll
      for (int fj = 0; fj < 4; ++fj) bf[fj] = *(const s16x8*)&Bs[wc + fj * 16 + lr][kk + 8 * lq];
      #pragma unroll
      for (int fi = 0; fi < 4; ++fi)
        #pragma unroll
        for (int fj = 0; fj < 4; ++fj)
          acc[fi][fj] = __builtin_amdgcn_mfma_f32_16x16x32_bf16(af[fi], bf[fj], acc[fi][fj], 0, 0, 0);
    }
  }
  #pragma unroll
  for (int fi = 0; fi < 4; ++fi)
    #pragma unroll
    for (int fj = 0; fj < 4; ++fj) {
      const int n = n0 + wc + fj * 16 + lr;
      const int mb = m0 + wr + fi * 16 + lq * 4;
      #pragma unroll
      for (int r = 0; r < 4; ++r) {
        const size_t idx = (size_t)(mb + r) * DIM + n;
        out[idx] = acc[fi][fj][r] * bf2f(xg[idx]) + out[idx];   // out holds xs (in-place)
      }
    }
}

extern "C" void kernel_launch(void* const* d_in, const int* in_sizes, int n_in,
                              void* d_out, int out_size, void* d_ws, size_t ws_size,
                              hipStream_t stream) {
  const float* x        = (const float*)d_in[0];
  const float* lg       = (const float*)d_in[1];
  const float* lb       = (const float*)d_in[2];
  const float* w_qk     = (const float*)d_in[3];
  const float* g4       = (const float*)d_in[4];
  const float* b4       = (const float*)d_in[5];
  const float* g2       = (const float*)d_in[6];
  const float* b2       = (const float*)d_in[7];
  const float* w_hidden = (const float*)d_in[8];
  const float* w_gate   = (const float*)d_in[9];
  const float* w_out    = (const float*)d_in[10];
  // ws layout (bytes), total 247,660,544 (~236 MiB):
  //   QK   bf16 @ 0             8,388,608   [dead after attn]
  //   GATE bf16 @ 8,388,608    33,554,432   [dead after attn]
  //   QM   f32  @ 41,943,040       65,536
  //   HIDT bf16 @ 42,008,576   33,554,432   [bg][e][j]
  //   XG   bf16 @ 75,563,008   33,554,432
  //   OUT4 bf16 @ 109,117,440 134,217,728
  //   W1T  bf16 @ 243,335,168   1,703,936   [1664][512]
  //   WT   bf16 @ 245,039,104   2,621,440   [512][2560]
  //   HIDR bf16 = overlay @ 0  33,554,432   (written by k_trh AFTER attn, over QK+GATE)
  // xs (f32) lives in d_out, overwritten in-place by k_gemm2m epilogue.
  if (ws_size < 247660544ull) return;
  char* ws = (char*)d_ws;
  u16*   QKb  = (u16*)  (ws + 0);
  u16*   GATE = (u16*)  (ws + 8388608);
  float* QM   = (float*)(ws + 41943040);
  u16*   HIDT = (u16*)  (ws + 42008576);
  u16*   XG   = (u16*)  (ws + 75563008);
  u16*   OUT4 = (u16*)  (ws + 109117440);
  u16*   W1T  = (u16*)  (ws + 243335168);
  u16*   WT   = (u16*)  (ws + 245039104);
  u16*   HIDR = (u16*)  (ws + 0);            // overlay
  float* XS   = (float*)d_out;
  float* OUT  = (float*)d_out;

  k_ln<<<BB * SEQ, 256, 0, stream>>>(x, lg, lb, XS);
  k_trw<<<dim3(8, 2),  256, 0, stream>>>(w_qk,     W1T, 128,  512,  0);
  k_trw<<<dim3(8, 16), 256, 0, stream>>>(w_hidden, W1T, 1024, 512,  128);
  k_trw<<<dim3(8, 8),  256, 0, stream>>>(w_gate,   W1T, 512,  512,  1152);
  k_trw<<<dim3(40, 8), 256, 0, stream>>>(w_out,    WT,  512,  2560, 0);
  k_gemm1m<<<dim3(256, 13), 256, 0, stream>>>(XS, W1T, QKb, HIDT, GATE, XG);
  k_qkmean<<<BB * GG, 128, 0, stream>>>(QKb, QM);
  k_attn<<<BB * GG * 4 * 4, 256, 0, stream>>>(QKb, QM, g4, b4, g2, b2, HIDT, GATE, OUT4);
  k_trh<<<dim3(4, 8, 128), 256, 0, stream>>>(HIDT, HIDR);
  k_gemm2m<<<dim3(256, 4), 256, 0, stream>>>(HIDR, OUT4, WT, XG, OUT);
}

// Round 5
// 676.548 us; speedup vs baseline: 8.8651x; 1.0102x over previous
//
#include <hip/hip_runtime.h>
#include <hip/hip_bf16.h>
#include <math.h>

#define BB 4
#define SEQ 8192
#define DIM 512
#define GG 32
#define NPG 256
#define QKD 128
#define HIDD 512

typedef unsigned short u16;
typedef unsigned int u32;

using s16x8 = __attribute__((ext_vector_type(8))) short;
using f32x4 = __attribute__((ext_vector_type(4))) float;

__device__ __forceinline__ float bf2f(u16 u) { return __uint_as_float(((u32)u) << 16); }
__device__ __forceinline__ u16 f2bf(float f) {
  u32 b = __float_as_uint(f);
  return (u16)((b + 0x7FFFu + ((b >> 16) & 1u)) >> 16);
}
__device__ __forceinline__ float silu_f(float x) { return x / (1.f + expf(-x)); }

// ---------------- Kernel 1: LayerNorm + global seq-shift scatter ----------------
__global__ __launch_bounds__(256) void k_ln(const float* __restrict__ x,
    const float* __restrict__ lg, const float* __restrict__ lb, float* __restrict__ xs) {
  const int row = blockIdx.x;               // b*SEQ + s
  const int s = row & (SEQ - 1);
  const int t = threadIdx.x;
  const float* xr = x + (size_t)row * DIM;
  float v0 = xr[t], v1 = xr[t + 256];
  float sum = v0 + v1, sq = v0 * v0 + v1 * v1;
  #pragma unroll
  for (int o = 32; o; o >>= 1) { sum += __shfl_down(sum, o); sq += __shfl_down(sq, o); }
  __shared__ float sm[8];
  const int w = t >> 6;
  if ((t & 63) == 0) { sm[w] = sum; sm[4 + w] = sq; }
  __syncthreads();
  if (t == 0) {
    float S = sm[0] + sm[1] + sm[2] + sm[3];
    float Q = sm[4] + sm[5] + sm[6] + sm[7];
    float mu = S * (1.f / DIM);
    float var = Q * (1.f / DIM) - mu * mu;
    sm[0] = mu; sm[4] = rsqrtf(var + 1e-5f);
  }
  __syncthreads();
  const float mu = sm[0], rs = sm[4];
  float y0 = (v0 - mu) * rs * lg[t] + lb[t];
  float y1 = (v1 - mu) * rs * lg[t + 256] + lb[t + 256];
  xs[(size_t)row * DIM + t + 256] = y1;
  if (s + 1 < SEQ) xs[(size_t)(row + 1) * DIM + t] = y0;
  if (s == 0) xs[(size_t)row * DIM + t] = 0.f;
}

// ---------------- weight transpose f32 [K][N] -> bf16 [rowOff+n][dstLD] ----------------
__global__ __launch_bounds__(256) void k_trw(const float* __restrict__ src, u16* __restrict__ dst,
    int N, int dstLD, int rowOff) {
  __shared__ u16 T[64][66];
  const int t = threadIdx.x;
  const int k0 = blockIdx.x * 64, n0 = blockIdx.y * 64;
  #pragma unroll
  for (int i = 0; i < 16; ++i) {
    int idx = t + 256 * i;
    int r = idx >> 6, c = idx & 63;            // r: k-dir, c: n-dir
    T[c][r] = f2bf(src[(size_t)(k0 + r) * N + n0 + c]);
  }
  __syncthreads();
  #pragma unroll
  for (int i = 0; i < 16; ++i) {
    int idx = t + 256 * i;
    int r = idx >> 6, c = idx & 63;            // r: n-dir, c: k-dir
    dst[(size_t)(rowOff + n0 + r) * dstLD + k0 + c] = T[r][c];
  }
}

// ---------------- HIDT [bg][e=512][j=256] -> HIDR [bg*256+j][512] (bf16) ----------------
__global__ __launch_bounds__(256) void k_trh(const u16* __restrict__ hidt, u16* __restrict__ hidr) {
  __shared__ u16 T[64][66];
  const int t = threadIdx.x;
  const int j0 = blockIdx.x * 64;
  const int e0 = blockIdx.y * 64;
  const int bg = blockIdx.z;
  #pragma unroll
  for (int i = 0; i < 16; ++i) {
    int idx = t + 256 * i; int r = idx >> 6, c = idx & 63;   // r: e, c: j
    T[c][r] = hidt[((size_t)bg * 512 + e0 + r) * 256 + j0 + c];
  }
  __syncthreads();
  #pragma unroll
  for (int i = 0; i < 16; ++i) {
    int idx = t + 256 * i; int r = idx >> 6, c = idx & 63;   // r: j, c: e
    hidr[((size_t)bg * 256 + j0 + r) * 512 + e0 + c] = T[r][c];
  }
}

// ---------------- Kernel 2: MFMA GEMM xs @ [w_qk | w_hidden | w_gate] ----------------
__global__ __launch_bounds__(256, 2) void k_gemm1m(const float* __restrict__ xs,
    const u16* __restrict__ w1t, u16* __restrict__ qk, u16* __restrict__ hidt,
    u16* __restrict__ gate, u16* __restrict__ xg) {
  __shared__ u16 As[128][72];
  __shared__ u16 Bs[128][72];
  const int t = threadIdx.x;
  const int m0 = blockIdx.x * 128, n0 = blockIdx.y * 128;
  const int w = t >> 6, l = t & 63, lr = l & 15, lq = l >> 4;
  const int wr = (w >> 1) * 64, wc = (w & 1) * 64;
  const int sr = t >> 3;            // 0..31 staging row
  const int sk = (t & 7) * 8;       // staging k elem offset
  f32x4 acc[4][4];
  #pragma unroll
  for (int i = 0; i < 4; ++i)
    #pragma unroll
    for (int j = 0; j < 4; ++j) acc[i][j] = (f32x4){0.f, 0.f, 0.f, 0.f};
  for (int k0 = 0; k0 < 512; k0 += 64) {
    s16x8 aS[4], bS[4];
    #pragma unroll
    for (int it = 0; it < 4; ++it) {
      const float* ap = xs + (size_t)(m0 + sr + it * 32) * 512 + k0 + sk;
      float4 f0 = *(const float4*)ap;
      float4 f1 = *(const float4*)(ap + 4);
      s16x8 v;
      v[0] = (short)f2bf(f0.x); v[1] = (short)f2bf(f0.y); v[2] = (short)f2bf(f0.z); v[3] = (short)f2bf(f0.w);
      v[4] = (short)f2bf(f1.x); v[5] = (short)f2bf(f1.y); v[6] = (short)f2bf(f1.z); v[7] = (short)f2bf(f1.w);
      aS[it] = v;
      bS[it] = *(const s16x8*)(w1t + (size_t)(n0 + sr + it * 32) * 512 + k0 + sk);
    }
    __syncthreads();
    #pragma unroll
    for (int it = 0; it < 4; ++it) {
      *(s16x8*)&As[sr + it * 32][sk] = aS[it];
      *(s16x8*)&Bs[sr + it * 32][sk] = bS[it];
    }
    __syncthreads();
    #pragma unroll
    for (int kk = 0; kk < 64; kk += 32) {
      s16x8 af[4], bf[4];
      #pragma unroll
      for (int fi = 0; fi < 4; ++fi) af[fi] = *(const s16x8*)&As[wr + fi * 16 + lr][kk + 8 * lq];
      #pragma unroll
      for (int fj = 0; fj < 4; ++fj) bf[fj] = *(const s16x8*)&Bs[wc + fj * 16 + lr][kk + 8 * lq];
      #pragma unroll
      for (int fi = 0; fi < 4; ++fi)
        #pragma unroll
        for (int fj = 0; fj < 4; ++fj)
          acc[fi][fj] = __builtin_amdgcn_mfma_f32_16x16x32_bf16(af[fi], bf[fj], acc[fi][fj], 0, 0, 0);
    }
  }
  // epilogue (segment is block-uniform: boundaries are 128-aligned)
  if (n0 == 0) {
    #pragma unroll
    for (int fi = 0; fi < 4; ++fi)
      #pragma unroll
      for (int fj = 0; fj < 4; ++fj) {
        const int n = wc + fj * 16 + lr;
        const int mb = m0 + wr + fi * 16 + lq * 4;
        #pragma unroll
        for (int r = 0; r < 4; ++r)
          qk[(size_t)(mb + r) * QKD + n] = f2bf(acc[fi][fj][r]);
      }
  } else if (n0 < 640) {
    const int bg = m0 >> 8;
    #pragma unroll
    for (int fi = 0; fi < 4; ++fi)
      #pragma unroll
      for (int fj = 0; fj < 4; ++fj) {
        const int e = n0 - 128 + wc + fj * 16 + lr;
        const int j0 = (m0 & 255) + wr + fi * 16 + lq * 4;
        ushort4 pk;
        pk.x = f2bf(acc[fi][fj][0]); pk.y = f2bf(acc[fi][fj][1]);
        pk.z = f2bf(acc[fi][fj][2]); pk.w = f2bf(acc[fi][fj][3]);
        *(ushort4*)(hidt + ((size_t)bg * 512 + e) * 256 + j0) = pk;
      }
  } else if (n0 < 1152) {
    #pragma unroll
    for (int fi = 0; fi < 4; ++fi)
      #pragma unroll
      for (int fj = 0; fj < 4; ++fj) {
        const int n = n0 - 640 + wc + fj * 16 + lr;
        const int mb = m0 + wr + fi * 16 + lq * 4;
        #pragma unroll
        for (int r = 0; r < 4; ++r)
          gate[(size_t)(mb + r) * HIDD + n] = f2bf(acc[fi][fj][r]);
      }
  } else {
    #pragma unroll
    for (int fi = 0; fi < 4; ++fi)
      #pragma unroll
      for (int fj = 0; fj < 4; ++fj) {
        const int n = n0 - 1152 + wc + fj * 16 + lr;
        const int mb = m0 + wr + fi * 16 + lq * 4;
        #pragma unroll
        for (int r = 0; r < 4; ++r)
          xg[(size_t)(mb + r) * HIDD + n] = f2bf(silu_f(acc[fi][fj][r]));
      }
  }
}

// ---------------- Kernel 3: qk_mean over each group's 256 rows ----------------
__global__ __launch_bounds__(128) void k_qkmean(const u16* __restrict__ qk, float* __restrict__ qm) {
  const int bg = blockIdx.x;
  const int c = threadIdx.x;
  const u16* p = qk + (size_t)bg * NPG * QKD + c;
  float s = 0.f;
  for (int i = 0; i < NPG; ++i) s += bf2f(p[(size_t)i * QKD]);
  qm[(size_t)bg * QKD + c] = s * (1.f / NPG);
}

// ---------------- Kernel 4: swapped-operand MFMA attention ----------------
// Block = (b,g,h, 64 q-rows), 4 waves x 16 q-rows. QK^T computed TRANSPOSED:
// mfma(A=K, B=Q) -> lane holds S[i=lr][j=nt*16+lq*4+r]  (one q-row per lane).
// Softmax: per-lane + shfl_xor(16,32). P^T B-frags for PV built via in-wave shuffles.
// PV: mfma(A=V^T from HIDT, B=P^T) -> D[e][i]; epilogue vectorized ushort4.
__global__ __launch_bounds__(256, 3) void k_attn(const u16* __restrict__ qk,
    const float* __restrict__ qm, const float* __restrict__ g4, const float* __restrict__ b4,
    const float* __restrict__ g2, const float* __restrict__ b2,
    const u16* __restrict__ hidt, const u16* __restrict__ gate, u16* __restrict__ out4) {
  __shared__ u16 Ks[256][72];
  __shared__ u16 Qs[64][72];
  const int t = threadIdx.x;
  const int blk = blockIdx.x;
  const int rb = blk & 3, h = (blk >> 2) & 3, bg = blk >> 4;
  const size_t grpRow = (size_t)bg * NPG;
  const int cbase = (h & 1) << 6;
  // ---- stage K (causally-bounded) and Q (64 rows), affine-transformed bf16 ----
  const int d = t & 63, ccol = cbase + d;
  const float qmv = qm[(size_t)bg * QKD + ccol];
  const float qof = qmv * g4[ccol] + b4[ccol];
  const float kof = qmv * g4[QKD + ccol] + b4[QKD + ccol];
  const float qsc = qmv * g4[2 * QKD + ccol] + b4[2 * QKD + ccol];
  const float ksc = qmv * g4[3 * QKD + ccol] + b4[3 * QKD + ccol];
  const float qso = qmv * g2[ccol] + b2[ccol];
  const float kso = qmv * g2[QKD + ccol] + b2[QKD + ccol];
  const int jstage = (rb + 1) * 64;
  for (int j = t >> 6; j < jstage; j += 4) {
    float kv;
    if (h < 2) kv = bf2f(qk[(grpRow + j) * QKD + ccol]) * ksc + kof;
    else {
      float prev = j ? (bf2f(qk[(grpRow + j - 1) * QKD + ccol]) * ksc + kof) : 0.f;
      kv = prev * ksc + kso;
    }
    Ks[j][d] = f2bf(kv);
  }
  for (int i = t >> 6; i < 64; i += 4) {
    int gi = rb * 64 + i;
    float qv;
    if (h < 2) qv = bf2f(qk[(grpRow + gi) * QKD + ccol]) * qsc + qof;
    else {
      float prev = gi ? (bf2f(qk[(grpRow + gi - 1) * QKD + ccol]) * qsc + qof) : 0.f;
      qv = prev * qsc + qso;
    }
    Qs[i][d] = f2bf(qv);
  }
  __syncthreads();
  // ---- per-wave independent from here (no more barriers) ----
  const int w = t >> 6, l = t & 63;
  const int lr = l & 15, lq = l >> 4;
  const int iw = rb * 4 + w;          // i-tile index 0..15
  const int i0 = iw * 16;
  const int ntmax = iw;               // causal QK col-tile bound
  const int jtmax = iw >> 1;          // causal PV j-tile bound
  const int irow = i0 + lr;           // this lane's query row
  // Q as B-operand (B[k][col=i=lr] = Q[i][k]) — two 32-k slices
  s16x8 qb0 = *(const s16x8*)&Qs[w * 16 + lr][8 * lq];
  s16x8 qb1 = *(const s16x8*)&Qs[w * 16 + lr][32 + 8 * lq];
  f32x4 sfr[16];
  #pragma unroll
  for (int nt = 0; nt < 16; ++nt) {
    if (nt <= ntmax) {
      s16x8 ka0 = *(const s16x8*)&Ks[nt * 16 + lr][8 * lq];
      s16x8 ka1 = *(const s16x8*)&Ks[nt * 16 + lr][32 + 8 * lq];
      f32x4 c = {0.f, 0.f, 0.f, 0.f};
      c = __builtin_amdgcn_mfma_f32_16x16x32_bf16(ka0, qb0, c, 0, 0, 0);
      c = __builtin_amdgcn_mfma_f32_16x16x32_bf16(ka1, qb1, c, 0, 0, 0);
      sfr[nt] = c;
    }
  }
  // ---- softmax over j for this lane's row i ----
  const float scl = 0.17677669529663687f;   // 1/sqrt(32)
  float mx = -3.4e38f;
  #pragma unroll
  for (int nt = 0; nt < 16; ++nt) if (nt <= ntmax) {
    #pragma unroll
    for (int r = 0; r < 4; ++r) {
      int j = nt * 16 + lq * 4 + r;
      if (j <= irow) mx = fmaxf(mx, sfr[nt][r] * scl);
    }
  }
  mx = fmaxf(mx, __shfl_xor(mx, 16));
  mx = fmaxf(mx, __shfl_xor(mx, 32));
  float sum = 0.f;
  u32 p01[16], p23[16];
  #pragma unroll
  for (int nt = 0; nt < 16; ++nt) { p01[nt] = 0u; p23[nt] = 0u; }
  #pragma unroll
  for (int nt = 0; nt < 16; ++nt) if (nt <= ntmax) {
    float e0, e1, e2, e3;
    {
      int j = nt * 16 + lq * 4;
      e0 = (j + 0 <= irow) ? expf(sfr[nt][0] * scl - mx) : 0.f;
      e1 = (j + 1 <= irow) ? expf(sfr[nt][1] * scl - mx) : 0.f;
      e2 = (j + 2 <= irow) ? expf(sfr[nt][2] * scl - mx) : 0.f;
      e3 = (j + 3 <= irow) ? expf(sfr[nt][3] * scl - mx) : 0.f;
    }
    sum += (e0 + e1) + (e2 + e3);
    p01[nt] = (u32)f2bf(e0) | ((u32)f2bf(e1) << 16);
    p23[nt] = (u32)f2bf(e2) | ((u32)f2bf(e3) << 16);
  }
  sum += __shfl_xor(sum, 16);
  sum += __shfl_xor(sum, 32);
  const float inv = 1.f / sum;
  // ---- build P^T B-frags via in-wave shuffles ----
  // dest lane (lq,lr) elem ii: j = 32*jt + 8*lq + ii, i = lr.
  // packs live at lane lr+16*lq', frag 2jt+(lq>>1): ii0-3 from lq'=2(lq&1), ii4-7 from +1.
  const int srcA = (l & 15) | ((l & 16) << 1);   // lr + 32*(lq&1)
  const int srcB = srcA + 16;
  const bool hi = (l >= 32);
  s16x8 bfr[8];
  #pragma unroll
  for (int jt = 0; jt < 8; ++jt) if (jt <= jtmax) {
    u32 a0 = __shfl((int)p01[2 * jt], srcA), a1 = __shfl((int)p23[2 * jt], srcA);
    u32 a2 = __shfl((int)p01[2 * jt], srcB), a3 = __shfl((int)p23[2 * jt], srcB);
    u32 b0 = __shfl((int)p01[2 * jt + 1], srcA), b1 = __shfl((int)p23[2 * jt + 1], srcA);
    u32 b2 = __shfl((int)p01[2 * jt + 1], srcB), b3 = __shfl((int)p23[2 * jt + 1], srcB);
    union { u32 u[4]; s16x8 v; } bb;
    bb.u[0] = hi ? b0 : a0; bb.u[1] = hi ? b1 : a1;
    bb.u[2] = hi ? b2 : a2; bb.u[3] = hi ? b3 : a3;
    bfr[jt] = bb.v;
  }
  // ---- PV: D[e][i] = sum_j V^T[e][j] P^T[j][i], 4 e-quarters of 128 ----
  const u16* vt = hidt + (size_t)bg * (512 * 256);
  const size_t srow = grpRow + irow;
  const u16* gp = gate + srow * HIDD;
  u16* op = out4 + srow * 2048 + ((size_t)h << 9);
  #pragma unroll
  for (int qtr = 0; qtr < 4; ++qtr) {
    f32x4 acc[8];
    #pragma unroll
    for (int ef = 0; ef < 8; ++ef) acc[ef] = (f32x4){0.f, 0.f, 0.f, 0.f};
    #pragma unroll
    for (int jt = 0; jt < 8; ++jt) if (jt <= jtmax) {
      __builtin_amdgcn_s_setprio(1);
      #pragma unroll
      for (int ef = 0; ef < 8; ++ef) {
        const int e = qtr * 128 + ef * 16 + lr;
        s16x8 va = *(const s16x8*)(vt + (size_t)e * 256 + jt * 32 + 8 * lq);
        acc[ef] = __builtin_amdgcn_mfma_f32_16x16x32_bf16(va, bfr[jt], acc[ef], 0, 0, 0);
      }
      __builtin_amdgcn_s_setprio(0);
    }
    #pragma unroll
    for (int ef = 0; ef < 8; ++ef) {
      const int e = qtr * 128 + ef * 16 + lq * 4;
      ushort4 gu = *(const ushort4*)(gp + e);
      ushort4 ov;
      ov.x = f2bf(silu_f(acc[ef][0] * inv) * bf2f(gu.x));
      ov.y = f2bf(silu_f(acc[ef][1] * inv) * bf2f(gu.y));
      ov.z = f2bf(silu_f(acc[ef][2] * inv) * bf2f(gu.z));
      ov.w = f2bf(silu_f(acc[ef][3] * inv) * bf2f(gu.w));
      *(ushort4*)(op + e) = ov;
    }
  }
}

// ---------------- Kernel 5: MFMA GEMM residual(2560) @ w_out + epilogue ----------------
__global__ __launch_bounds__(256, 2) void k_gemm2m(const u16* __restrict__ hidr,
    const u16* __restrict__ out4, const u16* __restrict__ wt,
    const u16* __restrict__ xg, float* __restrict__ out) {
  __shared__ u16 As[128][72];
  __shared__ u16 Bs[128][72];
  const int t = threadIdx.x;
  const int m0 = blockIdx.x * 128, n0 = blockIdx.y * 128;
  const int w = t >> 6, l = t & 63, lr = l & 15, lq = l >> 4;
  const int wr = (w >> 1) * 64, wc = (w & 1) * 64;
  const int sr = t >> 3;
  const int sk = (t & 7) * 8;
  f32x4 acc[4][4];
  #pragma unroll
  for (int i = 0; i < 4; ++i)
    #pragma unroll
    for (int j = 0; j < 4; ++j) acc[i][j] = (f32x4){0.f, 0.f, 0.f, 0.f};
  for (int k0 = 0; k0 < 2560; k0 += 64) {
    const u16* abase; size_t ald; int koff;
    if (k0 < 512) { abase = hidr; ald = 512; koff = k0; }
    else          { abase = out4; ald = 2048; koff = k0 - 512; }
    s16x8 aS[4], bS[4];
    #pragma unroll
    for (int it = 0; it < 4; ++it) {
      aS[it] = *(const s16x8*)(abase + (size_t)(m0 + sr + it * 32) * ald + koff + sk);
      bS[it] = *(const s16x8*)(wt + (size_t)(n0 + sr + it * 32) * 2560 + k0 + sk);
    }
    __syncthreads();
    #pragma unroll
    for (int it = 0; it < 4; ++it) {
      *(s16x8*)&As[sr + it * 32][sk] = aS[it];
      *(s16x8*)&Bs[sr + it * 32][sk] = bS[it];
    }
    __syncthreads();
    #pragma unroll
    for (int kk = 0; kk < 64; kk += 32) {
      s16x8 af[4], bf[4];
      #pragma unroll
      for (int fi = 0; fi < 4; ++fi) af[fi] = *(const s16x8*)&As[wr + fi * 16 + lr][kk + 8 * lq];
      #pragma unroll
      for (int fj = 0; fj < 4; ++fj) bf[fj] = *(const s16x8*)&Bs[wc + fj * 16 + lr][kk + 8 * lq];
      #pragma unroll
      for (int fi = 0; fi < 4; ++fi)
        #pragma unroll
        for (int fj = 0; fj < 4; ++fj)
          acc[fi][fj] = __builtin_amdgcn_mfma_f32_16x16x32_bf16(af[fi], bf[fj], acc[fi][fj], 0, 0, 0);
    }
  }
  #pragma unroll
  for (int fi = 0; fi < 4; ++fi)
    #pragma unroll
    for (int fj = 0; fj < 4; ++fj) {
      const int n = n0 + wc + fj * 16 + lr;
      const int mb = m0 + wr + fi * 16 + lq * 4;
      #pragma unroll
      for (int r = 0; r < 4; ++r) {
        const size_t idx = (size_t)(mb + r) * DIM + n;
        out[idx] = acc[fi][fj][r] * bf2f(xg[idx]) + out[idx];   // out holds xs (in-place)
      }
    }
}

extern "C" void kernel_launch(void* const* d_in, const int* in_sizes, int n_in,
                              void* d_out, int out_size, void* d_ws, size_t ws_size,
                              hipStream_t stream) {
  const float* x        = (const float*)d_in[0];
  const float* lg       = (const float*)d_in[1];
  const float* lb       = (const float*)d_in[2];
  const float* w_qk     = (const float*)d_in[3];
  const float* g4       = (const float*)d_in[4];
  const float* b4       = (const float*)d_in[5];
  const float* g2       = (const float*)d_in[6];
  const float* b2       = (const float*)d_in[7];
  const float* w_hidden = (const float*)d_in[8];
  const float* w_gate   = (const float*)d_in[9];
  const float* w_out    = (const float*)d_in[10];
  // ws layout (bytes), total 247,660,544 (~236 MiB):
  //   QK   bf16 @ 0             8,388,608   [dead after attn]
  //   GATE bf16 @ 8,388,608    33,554,432   [dead after attn]
  //   QM   f32  @ 41,943,040       65,536
  //   HIDT bf16 @ 42,008,576   33,554,432   [bg][e][j]
  //   XG   bf16 @ 75,563,008   33,554,432
  //   OUT4 bf16 @ 109,117,440 134,217,728
  //   W1T  bf16 @ 243,335,168   1,703,936   [1664][512]
  //   WT   bf16 @ 245,039,104   2,621,440   [512][2560]
  //   HIDR bf16 = overlay @ 0  33,554,432   (written by k_trh AFTER attn, over QK+GATE)
  // xs (f32) lives in d_out, overwritten in-place by k_gemm2m epilogue.
  if (ws_size < 247660544ull) return;
  char* ws = (char*)d_ws;
  u16*   QKb  = (u16*)  (ws + 0);
  u16*   GATE = (u16*)  (ws + 8388608);
  float* QM   = (float*)(ws + 41943040);
  u16*   HIDT = (u16*)  (ws + 42008576);
  u16*   XG   = (u16*)  (ws + 75563008);
  u16*   OUT4 = (u16*)  (ws + 109117440);
  u16*   W1T  = (u16*)  (ws + 243335168);
  u16*   WT   = (u16*)  (ws + 245039104);
  u16*   HIDR = (u16*)  (ws + 0);            // overlay
  float* XS   = (float*)d_out;
  float* OUT  = (float*)d_out;

  k_ln<<<BB * SEQ, 256, 0, stream>>>(x, lg, lb, XS);
  k_trw<<<dim3(8, 2),  256, 0, stream>>>(w_qk,     W1T, 128,  512,  0);
  k_trw<<<dim3(8, 16), 256, 0, stream>>>(w_hidden, W1T, 1024, 512,  128);
  k_trw<<<dim3(8, 8),  256, 0, stream>>>(w_gate,   W1T, 512,  512,  1152);
  k_trw<<<dim3(40, 8), 256, 0, stream>>>(w_out,    WT,  512,  2560, 0);
  k_gemm1m<<<dim3(256, 13), 256, 0, stream>>>(XS, W1T, QKb, HIDT, GATE, XG);
  k_qkmean<<<BB * GG, 128, 0, stream>>>(QKb, QM);
  k_attn<<<BB * GG * 4 * 4, 256, 0, stream>>>(QKb, QM, g4, b4, g2, b2, HIDT, GATE, OUT4);
  k_trh<<<dim3(4, 8, 128), 256, 0, stream>>>(HIDT, HIDR);
  k_gemm2m<<<dim3(256, 4), 256, 0, stream>>>(HIDR, OUT4, WT, XG, OUT);
}